// Round 14
// baseline (134.377 us; speedup 1.0000x reference)
//
#include <hip/hip_runtime.h>

// Problem constants (from reference)
#define N_NODES 2048
#define C_CH    128
#define NIRR    9
#define E_EL    10
// dslot mapping: 0 -> l0 (d=0), 1..3 -> l1 (d=0..2)

// Symmetrized coupling tables, role-major so each wave (one role r = ds)
// scalar-loads a contiguous 8B-aligned slice:
//   us3: [r(4)][s3(165)][k(4)]      = 2640 floats
//   us2: [r(4)][s2(45)][k(4 pad)]   =  720 floats (k=3 zero)
//   us1: [r(4)][p(9)][k(2)]         =   72 floats
#define NS3 165
#define NS2 45
#define US3_FLOATS (NS3 * 16)       // 2640
#define US2_FLOATS (NS2 * 16)       //  720 (padded)
#define US1_FLOATS (9 * 8)          //   72

typedef float pf2 __attribute__((ext_vector_type(2)));

// Compile-time index tables for the flattened symmetric triple loop.
struct Tab {
    unsigned char pairP[NS2], pairQ[NS2];
    unsigned char triPair[NS3], triI[NS3];
};
constexpr Tab makeTab() {
    Tab t{};
    int s2 = 0, s3 = 0;
    for (int p = 0; p < 9; p++)
        for (int q = p; q < 9; q++) {
            t.pairP[s2] = (unsigned char)p;
            t.pairQ[s2] = (unsigned char)q;
            for (int i = q; i < 9; i++) {
                t.triPair[s3] = (unsigned char)s2;
                t.triI[s3] = (unsigned char)i;
                s3++;
            }
            s2++;
        }
    return t;
}
constexpr Tab TAB = makeTab();

// Symmetrize u3/u2/u1 over index-permutation orbits.
__global__ __launch_bounds__(256) void build_sym_kernel(
    const float* __restrict__ u3_l0, const float* __restrict__ u2_l0, const float* __restrict__ u1_l0,
    const float* __restrict__ u3_l1, const float* __restrict__ u2_l1, const float* __restrict__ u1_l1,
    float* __restrict__ us3, float* __restrict__ us2, float* __restrict__ us1)
{
    int t = blockIdx.x * 256 + threadIdx.x;
    if (t < US3_FLOATS) {
        int k = t & 3;
        int rs = t >> 2;
        int s = rs % NS3;
        int ds = rs / NS3;
        int pp = 0, qq = 0, ii = 0, cntr = 0;
        for (int p = 0; p < 9; p++)
            for (int q = p; q < 9; q++)
                for (int i = q; i < 9; i++) {
                    if (cntr == s) { pp = p; qq = q; ii = i; }
                    cntr++;
                }
        const float* u = (ds == 0) ? u3_l0 : (u3_l1 + (ds - 1) * 2916);
        int perm[6][3] = {{pp,qq,ii},{pp,ii,qq},{qq,pp,ii},{qq,ii,pp},{ii,pp,qq},{ii,qq,pp}};
        float acc = 0.f;
        #pragma unroll
        for (int j = 0; j < 6; j++)
            acc += u[((perm[j][0] * 9 + perm[j][1]) * 9 + perm[j][2]) * 4 + k];
        float mult = (pp == qq && qq == ii) ? 6.f : ((pp == qq || qq == ii) ? 2.f : 1.f);
        us3[ds * (NS3 * 4) + s * 4 + k] = acc / mult;
    } else if (t < US3_FLOATS + US2_FLOATS) {
        int t2 = t - US3_FLOATS;
        int k = t2 & 3;
        int rs = t2 >> 2;
        int s = rs % NS2;
        int ds = rs / NS2;
        float v = 0.f;
        if (k < 3) {
            int pp = 0, qq = 0, cntr = 0;
            for (int p = 0; p < 9; p++)
                for (int q = p; q < 9; q++) {
                    if (cntr == s) { pp = p; qq = q; }
                    cntr++;
                }
            const float* u = (ds == 0) ? u2_l0 : (u2_l1 + (ds - 1) * 243);
            float acc = u[(pp * 9 + qq) * 3 + k] + u[(qq * 9 + pp) * 3 + k];
            v = (pp == qq) ? acc * 0.5f : acc;
        }
        us2[ds * (NS2 * 4) + s * 4 + k] = v;
    } else if (t < US3_FLOATS + US2_FLOATS + US1_FLOATS) {
        int t1 = t - US3_FLOATS - US2_FLOATS;
        int p = t1 >> 3, dk = t1 & 7, ds = dk >> 1, k = dk & 1;
        const float* u = (ds == 0) ? u1_l0 : (u1_l1 + (ds - 1) * 18);
        us1[ds * 18 + p * 2 + k] = u[p * 2 + k];
    }
}

// Fused contraction + o3.Linear + skip. TWO nodes per block, 2 nodes/thread.
// Block = 512 = 128 c x 4 roles; role r computes dslot r for BOTH nodes.
// The wave-uniform table s_loads are the R12 bottleneck (43% VALUBusy, rest
// lgkm stalls); processing 2 nodes doubles the pk_fma consumed per s_load
// batch -> halves stall exposure per node. Packed 2xfp32 accumulation.
// NOTE: VGPR cap must stay >=128: (512,4) -> 128. R5's 64-cap spilled (14x).
__global__ __launch_bounds__(512, 4) void fused_kernel(
    const float* __restrict__ x, const float* __restrict__ y,
    const float* __restrict__ us3, const float* __restrict__ us2, const float* __restrict__ us1,
    const float* __restrict__ w3_l0, const float* __restrict__ w2_l0, const float* __restrict__ w1_l0,
    const float* __restrict__ w3_l1, const float* __restrict__ w2_l1, const float* __restrict__ w1_l1,
    const float* __restrict__ lw0, const float* __restrict__ lw1,
    const float* __restrict__ sc, float* __restrict__ out)
{
    __shared__ float fs[2][4][132];   // [node][dslot][c]
    int tid = threadIdx.x;
    int c = tid & 127;
    int r = __builtin_amdgcn_readfirstlane(tid >> 7);   // role == dslot, wave-uniform
    int b0 = blockIdx.x * 2;

    int e0 = 0, e1 = 0;
    #pragma unroll
    for (int k = 1; k < E_EL; k++) {
        if (y[b0 * E_EL + k] > 0.5f) e0 = k;
        if (y[(b0 + 1) * E_EL + k] > 0.5f) e1 = k;
    }
    e0 = __builtin_amdgcn_readfirstlane(e0);
    e1 = __builtin_amdgcn_readfirstlane(e1);

    float xv0[9], xv1[9];
    {
        const float* xp0 = x + ((size_t)b0 * C_CH + c) * NIRR;
        const float* xp1 = x + ((size_t)(b0 + 1) * C_CH + c) * NIRR;
        #pragma unroll
        for (int i = 0; i < 9; i++) { xv0[i] = xp0[i]; xv1[i] = xp1[i]; }
    }

    const float* t3 = us3 + r * (NS3 * 4);
    const float* t2 = us2 + r * (NS2 * 4);
    const float* t1 = us1 + r * 18;
    const pf2* T3v = (const pf2*)t3;
    const pf2* T2v = (const pf2*)t2;
    const pf2* T1v = (const pf2*)t1;

    pf2 G3a0 = {0.f, 0.f}, G3b0 = {0.f, 0.f}, G3a1 = {0.f, 0.f}, G3b1 = {0.f, 0.f};
    pf2 G2a0 = {0.f, 0.f}, G2a1 = {0.f, 0.f};
    float G2c0 = 0.f, G2c1 = 0.f;
    pf2 G1v0 = {0.f, 0.f}, G1v1 = {0.f, 0.f};

    #pragma unroll
    for (int p = 0; p < 9; p++) {
        pf2 u1v = T1v[p];
        pf2 xa = {xv0[p], xv0[p]};
        pf2 xb = {xv1[p], xv1[p]};
        G1v0 = __builtin_elementwise_fma(u1v, xa, G1v0);
        G1v1 = __builtin_elementwise_fma(u1v, xb, G1v1);
    }

    float pq0 = 0.f, pq1 = 0.f;
    #pragma unroll
    for (int s = 0; s < NS3; s++) {
        const int pi = TAB.triPair[s];
        if (s == 0 || TAB.triPair[s] != TAB.triPair[s - 1]) {
            pq0 = xv0[TAB.pairP[pi]] * xv0[TAB.pairQ[pi]];
            pq1 = xv1[TAB.pairP[pi]] * xv1[TAB.pairQ[pi]];
            pf2 u2v = T2v[pi * 2];
            float u2c = t2[pi * 4 + 2];
            pf2 pa = {pq0, pq0};
            pf2 pb = {pq1, pq1};
            G2a0 = __builtin_elementwise_fma(u2v, pa, G2a0);
            G2a1 = __builtin_elementwise_fma(u2v, pb, G2a1);
            G2c0 = __builtin_fmaf(u2c, pq0, G2c0);
            G2c1 = __builtin_fmaf(u2c, pq1, G2c1);
        }
        float X0 = pq0 * xv0[TAB.triI[s]];
        float X1 = pq1 * xv1[TAB.triI[s]];
        pf2 ua = T3v[s * 2];
        pf2 ub = T3v[s * 2 + 1];
        pf2 Xa = {X0, X0};
        pf2 Xb = {X1, X1};
        G3a0 = __builtin_elementwise_fma(ua, Xa, G3a0);
        G3b0 = __builtin_elementwise_fma(ub, Xa, G3b0);
        G3a1 = __builtin_elementwise_fma(ua, Xb, G3a1);
        G3b1 = __builtin_elementwise_fma(ub, Xb, G3b1);
    }

    // element weights (lane c): w3 (E,4,C), w2 (E,3,C), w1 (E,2,C)
    const float* W3 = (r == 0) ? w3_l0 : w3_l1;
    const float* W2 = (r == 0) ? w2_l0 : w2_l1;
    const float* W1 = (r == 0) ? w1_l0 : w1_l1;
    {
        float G3n0[4] = {G3a0.x, G3a0.y, G3b0.x, G3b0.y};
        float G3n1[4] = {G3a1.x, G3a1.y, G3b1.x, G3b1.y};
        float G2n0[3] = {G2a0.x, G2a0.y, G2c0};
        float G2n1[3] = {G2a1.x, G2a1.y, G2c1};
        float G1n0[2] = {G1v0.x, G1v0.y};
        float G1n1[2] = {G1v1.x, G1v1.y};
        float acc0 = 0.f, acc1 = 0.f;
        #pragma unroll
        for (int k = 0; k < 4; k++) {
            acc0 += W3[(e0 * 4 + k) * 128 + c] * G3n0[k];
            acc1 += W3[(e1 * 4 + k) * 128 + c] * G3n1[k];
        }
        #pragma unroll
        for (int k = 0; k < 3; k++) {
            acc0 += W2[(e0 * 3 + k) * 128 + c] * G2n0[k];
            acc1 += W2[(e1 * 3 + k) * 128 + c] * G2n1[k];
        }
        #pragma unroll
        for (int k = 0; k < 2; k++) {
            acc0 += W1[(e0 * 2 + k) * 128 + c] * G1n0[k];
            acc1 += W1[(e1 * 2 + k) * 128 + c] * G1n1[k];
        }
        fs[0][r][c] = acc0;
        fs[1][r][c] = acc1;
    }
    __syncthreads();

    // ---- o3.Linear + skip: threads 0..255; thread (n, t) owns 4 contiguous
    // j-cols of node b0+n. W reads coalesced dwordx4 (shared via L1 across n).
    if (tid < 256) {
        int n = tid >> 7;          // node select
        int t = tid & 127;
        int b = b0 + n;
        int sel, m = 0, j0;
        const float4* W4;
        bool isl0 = (t < 32);
        if (isl0) { sel = 0; j0 = 4 * t; W4 = (const float4*)lw0; }
        else {
            int idx = t - 32;
            m = idx >> 5;
            j0 = 4 * (idx & 31);
            sel = 1 + m;
            W4 = (const float4*)lw1;
        }
        int wbase = j0 >> 2;

        float a0 = 0.f, a1 = 0.f, a2 = 0.f, a3 = 0.f;
        #pragma unroll 4
        for (int ib = 0; ib < 32; ib++) {
            float4 f = *(const float4*)&fs[n][sel][4 * ib];
            float4 w0 = W4[(4 * ib + 0) * 32 + wbase];
            float4 w1 = W4[(4 * ib + 1) * 32 + wbase];
            float4 w2 = W4[(4 * ib + 2) * 32 + wbase];
            float4 w3 = W4[(4 * ib + 3) * 32 + wbase];
            a0 += f.x * w0.x + f.y * w1.x + f.z * w2.x + f.w * w3.x;
            a1 += f.x * w0.y + f.y * w1.y + f.z * w2.y + f.w * w3.y;
            a2 += f.x * w0.z + f.y * w1.z + f.z * w2.z + f.w * w3.z;
            a3 += f.x * w0.w + f.y * w1.w + f.z * w2.w + f.w * w3.w;
        }

        const float inv_sqrt_c = 0.08838834764831845f;  // 1/sqrt(128)
        if (isl0) {
            size_t o = (size_t)b * 512 + j0;
            float4 s = *(const float4*)(sc + o);
            float4 rr;
            rr.x = a0 * inv_sqrt_c + s.x;
            rr.y = a1 * inv_sqrt_c + s.y;
            rr.z = a2 * inv_sqrt_c + s.z;
            rr.w = a3 * inv_sqrt_c + s.w;
            *(float4*)(out + o) = rr;
        } else {
            float av[4] = {a0, a1, a2, a3};
            #pragma unroll
            for (int jj = 0; jj < 4; jj++) {
                size_t o = (size_t)b * 512 + 128 + 3 * (j0 + jj) + m;
                out[o] = av[jj] * inv_sqrt_c + sc[o];
            }
        }
    }
}

extern "C" void kernel_launch(void* const* d_in, const int* in_sizes, int n_in,
                              void* d_out, int out_size, void* d_ws, size_t ws_size,
                              hipStream_t stream) {
    const float* x     = (const float*)d_in[0];
    const float* y     = (const float*)d_in[1];
    const float* sc    = (const float*)d_in[2];
    const float* u3_l0 = (const float*)d_in[3];
    const float* u2_l0 = (const float*)d_in[4];
    const float* u1_l0 = (const float*)d_in[5];
    const float* w3_l0 = (const float*)d_in[6];
    const float* w2_l0 = (const float*)d_in[7];
    const float* w1_l0 = (const float*)d_in[8];
    const float* u3_l1 = (const float*)d_in[9];
    const float* u2_l1 = (const float*)d_in[10];
    const float* u1_l1 = (const float*)d_in[11];
    const float* w3_l1 = (const float*)d_in[12];
    const float* w2_l1 = (const float*)d_in[13];
    const float* w1_l1 = (const float*)d_in[14];
    const float* lw0   = (const float*)d_in[15];
    const float* lw1   = (const float*)d_in[16];
    float* out = (float*)d_out;

    // Workspace layout (floats): us3 | us2 | us1
    float* us3 = (float*)d_ws;
    float* us2 = us3 + US3_FLOATS;
    float* us1 = us2 + US2_FLOATS;

    int tot = US3_FLOATS + US2_FLOATS + US1_FLOATS;
    build_sym_kernel<<<(tot + 255) / 256, 256, 0, stream>>>(
        u3_l0, u2_l0, u1_l0, u3_l1, u2_l1, u1_l1, us3, us2, us1);
    fused_kernel<<<N_NODES / 2, 512, 0, stream>>>(
        x, y, us3, us2, us1,
        w3_l0, w2_l0, w1_l0, w3_l1, w2_l1, w1_l1,
        lw0, lw1, sc, out);
}